// Round 6
// baseline (614.899 us; speedup 1.0000x reference)
//
#include <hip/hip_runtime.h>

typedef _Float16 f16;
typedef _Float16 f16x8 __attribute__((ext_vector_type(8)));
typedef float f32x4 __attribute__((ext_vector_type(4)));

#define IBN 0.9999950000374997f   /* 1/sqrt(1+1e-5) */

// ws layout (byte offsets, 16B-aligned). Total ~2.97 MB.
#define WS_XM    0u          // f32 xm[n][64c][25v]   = 1,638,400 B  (T-mean)
#define WS_X1X2  1638400u    // f32 x1x2[n][1200]     = 1,228,800 B
#define WS_SE    2867200u    // f32 se[n][64]         =    65,536 B
#define WS_ASYM  2932736u    // f32 asym[3*625]       =     7,500 B
#define WS_W3P   2940240u    // f16 w3p[12288]        =    24,576 B

// ---------------------------------------------------------------------------
// kxm: xm[n][c][v] = mean_t x[n,c,t,v]. One block per n. Thread (c=tid>>2,
// t4=tid&3) streams 100 contiguous float4 (16 t-rows of channel c);
// compile-time %25 rotation; 4-way LDS reduce per channel.
// ---------------------------------------------------------------------------
__global__ __launch_bounds__(256) void kxm(const float* __restrict__ x,
                                           float* __restrict__ xm)
{
  __shared__ float red[64*101];
  int n = blockIdx.x, tid = threadIdx.x;
  int c = tid >> 2, t4 = tid & 3;
  const float4* p = (const float4*)x + (size_t)n*25600 + c*400 + t4*100;
  float va[25];
  #pragma unroll
  for (int v = 0; v < 25; ++v) va[v] = 0.f;
  #pragma unroll
  for (int i = 0; i < 100; ++i) {
    float4 q4 = p[i];
    va[(4*i)   % 25] += q4.x;
    va[(4*i+1) % 25] += q4.y;
    va[(4*i+2) % 25] += q4.z;
    va[(4*i+3) % 25] += q4.w;
  }
  #pragma unroll
  for (int v = 0; v < 25; ++v) red[c*101 + t4*25 + v] = va[v];
  __syncthreads();
  for (int idx = tid; idx < 1600; idx += 256) {
    int cc = idx / 25, v = idx - cc*25;
    float s = red[cc*101 + v] + red[cc*101 + 25 + v]
            + red[cc*101 + 50 + v] + red[cc*101 + 75 + v];
    xm[(size_t)n*1600 + idx] = s * (1.0f/64.0f);
  }
}

// ---------------------------------------------------------------------------
// kse: per-n. x1/x2 rows from xm; SE gate (BN folded, analytic — softmax rows
// sum to 1 so pooled depends only on xm). Block 0 packs Asym=PA+PA^T and w3
// into MFMA A-frag order.
// ---------------------------------------------------------------------------
__global__ __launch_bounds__(256) void kse(
    const float* __restrict__ xm, const float* __restrict__ PA,
    const float* __restrict__ w1, const float* __restrict__ b1,
    const float* __restrict__ w2, const float* __restrict__ b2,
    const float* __restrict__ w3, const float* __restrict__ b3,
    const float* __restrict__ bn_w, const float* __restrict__ bn_b,
    const float* __restrict__ se_w1, const float* __restrict__ se_b1,
    const float* __restrict__ se_w2, const float* __restrict__ se_b2,
    float* __restrict__ x1x2_g, float* __restrict__ se_g,
    float* __restrict__ asym_g, f16* __restrict__ w3p_g)
{
  __shared__ float xms[1600];
  __shared__ float w1s[1536], w2s[1536];
  __shared__ float xmv[64], pooledv[64], hbuf[16];
  int n = blockIdx.x, tid = threadIdx.x;

  for (int i = tid; i < 1536; i += 256) { w1s[i] = w1[i]; w2s[i] = w2[i]; }
  for (int idx = tid; idx < 1600; idx += 256) xms[idx] = xm[(size_t)n*1600 + idx];
  __syncthreads();

  for (int idx = tid; idx < 600; idx += 256) {
    int sr = idx / 25, v = idx - sr*25;
    float a1 = b1[sr], a2 = b2[sr];
    for (int c = 0; c < 64; ++c) {
      float xv = xms[c*25 + v];
      a1 += xv * w1s[sr*64 + c];
      a2 += xv * w2s[sr*64 + c];
    }
    x1x2_g[(size_t)n*1200 + idx]       = a1;
    x1x2_g[(size_t)n*1200 + 600 + idx] = a2;
  }

  if (tid < 64) {
    float s = 0.f;
    #pragma unroll
    for (int v = 0; v < 25; ++v) s += xms[tid*25 + v];
    xmv[tid] = s * (1.0f/25.0f);
  }
  __syncthreads();
  if (tid < 64) {
    int o = tid;
    float p = b3[o] + b3[64 + o] + b3[128 + o];
    for (int c = 0; c < 64; ++c)
      p += xmv[c] * (w3[o*64 + c] + w3[4096 + o*64 + c] + w3[8192 + o*64 + c]);
    pooledv[o] = IBN * bn_w[o] * p + bn_b[o];
  }
  __syncthreads();
  if (tid < 16) {
    float hh = se_b1[tid];
    for (int o = 0; o < 64; ++o) hh += pooledv[o] * se_w1[tid*64 + o];
    hbuf[tid] = fmaxf(hh, 0.0f);
  }
  __syncthreads();
  if (tid < 64) {
    float t = se_b2[tid];
    for (int j = 0; j < 16; ++j) t += hbuf[j] * se_w2[tid*16 + j];
    se_g[(size_t)n*64 + tid] = 1.0f / (1.0f + __expf(-t));
  }

  if (n == 0) {
    for (int idx = tid; idx < 1875; idx += 256) {
      int s = idx / 625, rem = idx - s*625, u = rem / 25, v = rem - u*25;
      asym_g[idx] = PA[s*625 + u*25 + v] + PA[s*625 + v*25 + u];
    }
    // w3p[((mi*2+kk)*64+lane)*8+j] = w3[m=mi*16+(lane&15)][c=kk*32+(lane>>4)*8+j]
    for (int idx = tid; idx < 12288; idx += 256) {
      int j = idx & 7, lane = (idx >> 3) & 63, kk = (idx >> 9) & 1, mi = idx >> 10;
      int s = mi >> 2, o = ((mi & 3) << 4) + (lane & 15);
      int c = kk*32 + ((lane >> 4) << 3) + j;
      w3p_g[idx] = (f16)w3[(s*64 + o)*64 + c];
    }
  }
}

// ---------------------------------------------------------------------------
// kc: block = (n, t-tile of 8). 2048 blocks, LDS ~76.6 KB -> 2 blocks/CU.
// Per s: att = tanh(x1-x2) -> attT[uv][8r] (fast exp).
// Per (s,ob): pass1 m_pre scalar (round-0-proven path, w4/b4 scalar loads);
//   softmax over u + stage1 Z=W3*X+b3 (MFMA 16x16x32, proven layout) in one
//   phase; stage2 Y += Z*m^T (MFMA). Epilogue fuses BN+SE+residual+ReLU.
// ---------------------------------------------------------------------------
struct __align__(16) Sm2 {
  f16   xsT[200*72];     // [j=t*25+v][c], 28,800 B
  f16   attT[640*8];     // [uv][r], 16 B rows, 10,240 B (rows >=625 unused)
  f16   ms[16*800];      // [op][u*32+v], 25,600 B
  f16   zs[16*256];      // [op][t*32+v] t<8, 8,192 B (v=25..31 zeroed)
  float asym_s[625];     // per-s, f32, 2,500 B
  float x1s[200], x2s[200];
  float b3s[192];
  float ses[64], bnws[64], bnbs[64];
};                        // ~76.6 KB

__global__ __launch_bounds__(256, 2) void kc(
    const float* __restrict__ x, const float* __restrict__ alpha,
    const float* __restrict__ b3, const float* __restrict__ w4,
    const float* __restrict__ b4, const float* __restrict__ bn_w,
    const float* __restrict__ bn_b, const float* __restrict__ x1x2_g,
    const float* __restrict__ se_g, const float* __restrict__ asym_g,
    const f16* __restrict__ w3p_g, float* __restrict__ out)
{
  __shared__ Sm2 sm;
  int bid = blockIdx.x;
  int n = bid >> 3, th = bid & 7;
  int tid = threadIdx.x;
  int lane = tid & 63, w = tid >> 6, q = lane >> 4, l15 = lane & 15;

  // ---- preamble: X tile (8 t) -> xsT f16 transposed; consts; zs/ms K-pads
  {
    const float4* xf = (const float4*)(x + (size_t)n*102400 + th*200);
    #pragma unroll
    for (int it = 0; it < 13; ++it) {
      int idx = it*256 + tid;
      if (idx < 3200) {
        int c = idx / 50, j4 = idx - c*50;
        float4 v4 = xf[c*400 + j4];
        sm.xsT[(4*j4 + 0)*72 + c] = (f16)v4.x;
        sm.xsT[(4*j4 + 1)*72 + c] = (f16)v4.y;
        sm.xsT[(4*j4 + 2)*72 + c] = (f16)v4.z;
        sm.xsT[(4*j4 + 3)*72 + c] = (f16)v4.w;
      }
    }
    if (tid < 192) sm.b3s[tid] = b3[tid];
    if (tid < 64) {
      sm.ses[tid]  = se_g[(size_t)n*64 + tid];
      sm.bnws[tid] = bn_w[tid];
      sm.bnbs[tid] = bn_b[tid];
    }
    for (int i = tid; i < 896; i += 256) {      // zs v-pad zero (never rewritten)
      int op = i / 56, rem = i - op*56, t = rem / 7, v = 25 + (rem - t*7);
      sm.zs[op*256 + t*32 + v] = (f16)0.f;
    }
    for (int i = tid; i < 2800; i += 256) {     // ms v-pad zero (never rewritten)
      int op = i / 175, rem = i - op*175, u = rem / 7, v = 25 + (rem - u*7);
      sm.ms[op*800 + u*32 + v] = (f16)0.f;
    }
  }
  __syncthreads();

  const f16x8* w3pv = (const f16x8*)w3p_g;
  int u2 = 16 + l15; if (u2 > 24) u2 = 24;     // clamp; D-cols >=25 discarded

  f32x4 yacc[4][4][2];                          // [ob][i][ut]
  #pragma unroll
  for (int ob = 0; ob < 4; ++ob)
    #pragma unroll
    for (int i = 0; i < 4; ++i) {
      yacc[ob][i][0] = (f32x4){0.f,0.f,0.f,0.f};
      yacc[ob][i][1] = (f32x4){0.f,0.f,0.f,0.f};
    }

  for (int s = 0; s < 3; ++s) {
    // ---- per-s staging (x1/x2/asym); prev users are past end-of-ob barrier
    if (tid < 200) {
      sm.x1s[tid] = x1x2_g[(size_t)n*1200 + s*200 + tid];
      sm.x2s[tid] = x1x2_g[(size_t)n*1200 + 600 + s*200 + tid];
    }
    for (int i = tid; i < 625; i += 256) sm.asym_s[i] = asym_g[s*625 + i];
    __syncthreads();

    // ---- att = tanh(x1[r,u]-x2[r,v]) -> attT[uv][r]
    for (int i = tid; i < 5000; i += 256) {
      int uv = i >> 3, r = i & 7;
      int u = uv / 25, v = uv - u*25;
      float d = sm.x1s[r*25 + u] - sm.x2s[r*25 + v];
      float a = fabsf(d);
      float e = __expf(-2.0f*a);
      float t = (1.0f - e) / (1.0f + e);
      sm.attT[uv*8 + r] = (f16)(d < 0.f ? -t : t);
    }
    float alphav = alpha[s];
    __syncthreads();

    #pragma unroll
    for (int ob = 0; ob < 4; ++ob) {
      // ---- pass1: m_pre -> ms (scalar FMAs, round-0-proven path).
      //      w4/b4 are wave-uniform scalar loads (o,r,s loop constants).
      #pragma unroll
      for (int e = 0; e < 3; ++e) {
        int uv = tid + e*256;
        if (uv < 625) {
          int u = uv / 25, v = uv - u*25;
          float attv[8];
          #pragma unroll
          for (int r = 0; r < 8; ++r) attv[r] = (float)sm.attT[uv*8 + r];
          float asv = sm.asym_s[uv];
          #pragma unroll
          for (int op = 0; op < 16; ++op) {
            int o = ob*16 + op;
            float acc = b4[s*64 + o];
            #pragma unroll
            for (int r = 0; r < 8; ++r) acc += attv[r] * w4[(s*64 + o)*8 + r];
            sm.ms[op*800 + u*32 + v] = (f16)(acc*alphav + asv);
          }
        }
      }
      __syncthreads();

      // ---- softmax over u (per (op,v) col), in place on ms
      #pragma unroll
      for (int e2 = 0; e2 < 2; ++e2) {
        int col = tid + e2*256;
        if (col < 400) {
          int op = col / 25, v = col - op*25;
          float vals[25]; float mx = -1e30f;
          #pragma unroll
          for (int u = 0; u < 25; ++u) {
            float t2 = (float)sm.ms[op*800 + u*32 + v];
            vals[u] = t2; mx = fmaxf(mx, t2);
          }
          float sum = 0.f;
          #pragma unroll
          for (int u = 0; u < 25; ++u) { float ev = __expf(vals[u]-mx); vals[u] = ev; sum += ev; }
          float inv = 1.0f / sum;
          #pragma unroll
          for (int u = 0; u < 25; ++u) sm.ms[op*800 + u*32 + v] = (f16)(vals[u]*inv);
        }
      }

      // ---- stage1 (same phase as softmax; touches only xsT->zs):
      //      Z[o' 16][j=200] = W3*X + b3   (MFMA 16x16x32, proven layout)
      {
        int mi = s*4 + ob;
        f16x8 a0 = w3pv[(mi*2 + 0)*64 + lane];
        f16x8 a1 = w3pv[(mi*2 + 1)*64 + lane];
        for (int ni = w; ni < 13; ni += 4) {
          int row = ni*16 + l15;
          int rowc = row < 199 ? row : 199;            // clamp; dup cols discarded
          f16x8 bf0 = *(const f16x8*)&sm.xsT[rowc*72 + q*8];
          f16x8 bf1 = *(const f16x8*)&sm.xsT[rowc*72 + 32 + q*8];
          f32x4 acc = (f32x4){0.f,0.f,0.f,0.f};
          acc = __builtin_amdgcn_mfma_f32_16x16x32_f16(a0, bf0, acc, 0, 0, 0);
          acc = __builtin_amdgcn_mfma_f32_16x16x32_f16(a1, bf1, acc, 0, 0, 0);
          if (row < 200) {
            int t = row / 25, v = row - t*25;
            #pragma unroll
            for (int rg = 0; rg < 4; ++rg) {
              int op = q*4 + rg;
              sm.zs[op*256 + t*32 + v] = (f16)(acc[rg] + sm.b3s[s*64 + ob*16 + op]);
            }
          }
        }
      }
      __syncthreads();

      // ---- stage2: Y[t][u] += Z[t][v] * m[u][v]
      #pragma unroll
      for (int i = 0; i < 4; ++i) {
        int op = w*4 + i;
        f16x8 az  = *(const f16x8*)&sm.zs[op*256 + (l15 & 7)*32 + q*8];
        f16x8 bm0 = *(const f16x8*)&sm.ms[op*800 + l15*32 + q*8];
        f16x8 bm1 = *(const f16x8*)&sm.ms[op*800 + u2*32 + q*8];
        yacc[ob][i][0] = __builtin_amdgcn_mfma_f32_16x16x32_f16(az, bm0, yacc[ob][i][0], 0, 0, 0);
        yacc[ob][i][1] = __builtin_amdgcn_mfma_f32_16x16x32_f16(az, bm1, yacc[ob][i][1], 0, 0, 0);
      }
      __syncthreads();   // protect ms/zs for next (ob,s)
    }
  }

  // ---- epilogue: BN+SE+residual+ReLU. D rows m=t valid only for t<8 (q<2).
  if (q < 2) {
    #pragma unroll
    for (int ob = 0; ob < 4; ++ob) {
      #pragma unroll
      for (int i = 0; i < 4; ++i) {
        int op = w*4 + i, o = ob*16 + op;
        float sev   = sm.ses[o];
        float scale = IBN * sm.bnws[o] * sev;
        float bias  = sm.bnbs[o] * sev;
        #pragma unroll
        for (int ut = 0; ut < 2; ++ut) {
          int u = ut*16 + l15;
          if (u < 25) {
            #pragma unroll
            for (int rg = 0; rg < 4; ++rg) {
              int t = q*4 + rg;                        // t in 0..7
              float xres = (float)sm.xsT[(t*25 + u)*72 + o];
              float val = yacc[ob][i][ut][rg]*scale + bias + xres;
              out[(((size_t)n*64 + o)*64 + th*8 + t)*25 + u] = fmaxf(val, 0.0f);
            }
          }
        }
      }
    }
  }
}

// ---------------------------------------------------------------------------
extern "C" void kernel_launch(void* const* d_in, const int* in_sizes, int n_in,
                              void* d_out, int out_size, void* d_ws, size_t ws_size,
                              hipStream_t stream)
{
  const float* x    = (const float*)d_in[0];
  const float* PA   = (const float*)d_in[1];
  const float* alp  = (const float*)d_in[2];
  const float* w1   = (const float*)d_in[3];
  const float* b1   = (const float*)d_in[4];
  const float* w2   = (const float*)d_in[5];
  const float* b2   = (const float*)d_in[6];
  const float* w3   = (const float*)d_in[7];
  const float* b3   = (const float*)d_in[8];
  const float* w4   = (const float*)d_in[9];
  const float* b4   = (const float*)d_in[10];
  const float* bnw  = (const float*)d_in[11];
  const float* bnb  = (const float*)d_in[12];
  const float* sw1  = (const float*)d_in[13];
  const float* sb1  = (const float*)d_in[14];
  const float* sw2  = (const float*)d_in[15];
  const float* sb2  = (const float*)d_in[16];

  char* ws = (char*)d_ws;
  float* xm_g   = (float*)(ws + WS_XM);
  float* x1x2_g = (float*)(ws + WS_X1X2);
  float* se_g   = (float*)(ws + WS_SE);
  float* asym_g = (float*)(ws + WS_ASYM);
  f16*   w3p_g  = (f16*)(ws + WS_W3P);

  float* out = (float*)d_out;

  kxm<<<256, 256, 0, stream>>>(x, xm_g);
  kse<<<256, 256, 0, stream>>>(xm_g, PA, w1, b1, w2, b2, w3, b3, bnw, bnb,
                               sw1, sb1, sw2, sb2, x1x2_g, se_g, asym_g, w3p_g);
  kc<<<2048, 256, 0, stream>>>(x, alp, b3, w4, b4, bnw, bnb,
                               x1x2_g, se_g, asym_g, w3p_g, out);
}